// Round 7
// baseline (156.666 us; speedup 1.0000x reference)
//
#include <hip/hip_runtime.h>

#define L_LEN 32768
#define QMAXF 127.0f
#define TPB 4   // conv tiles (of 64 t) per block

typedef __attribute__((ext_vector_type(4))) int v4i;

// ws layout (floats):
//   [0..6144)    : amax partials, slot (ic*32 + b*4 + ch)*3 + k  (64*8*4*3)
//                  plain stores, every slot written exactly once -> no memset
//   [6144..6336) : rv_j = 1/(scl_j * s_x), j = 3*ic+k (ic-major)
//   [6336]       : s_x * s_w
//   byte 32768+  : wsa A fragments (quantized weights, i8, MFMA lane-chunk order)

// ---------------- pass 1: per-(ic,b,quarter) abs-max partials ----------------
// grid (64,8,4): quarter-row per block, 8 float4/thread batched into regs
// (guaranteed 8-deep MLP), wave reduce, plain stores to unique slots.
__global__ __launch_bounds__(256) void actamax_kernel(const float* __restrict__ x,
                                                      float* __restrict__ wsf) {
    const int ic = blockIdx.x, b = blockIdx.y, ch = blockIdx.z;
    const int tid = threadIdx.x;
    const float4* row = (const float4*)(x + ((size_t)(b*64 + ic) << 15));
    const int base = ch*2048 + tid;

    float4 vbuf[8];
    #pragma unroll
    for (int i = 0; i < 8; ++i) vbuf[i] = row[base + i*256];   // all 8 in flight

    float mA = 0.0f, mNF = 0.0f, mNL = 0.0f;   // all, no-first(t>0), no-last(t<L-1)
    #pragma unroll
    for (int i = 0; i < 8; ++i) {
        const int f = base + i*256;
        float4 v = vbuf[i];
        float ax = fabsf(v.x), ay = fabsf(v.y), az = fabsf(v.z), aw = fabsf(v.w);
        float m4 = fmaxf(fmaxf(ax, ay), fmaxf(az, aw));
        mA = fmaxf(mA, m4);
        if (f == 0) {                      // only ch==0,i==0,tid==0
            mNF = fmaxf(mNF, fmaxf(ay, fmaxf(az, aw)));
            mNL = fmaxf(mNL, m4);
        } else if (f == 8191) {            // only ch==3,i==7,tid==255
            mNF = fmaxf(mNF, m4);
            mNL = fmaxf(mNL, fmaxf(ax, fmaxf(ay, az)));
        } else {
            mNF = fmaxf(mNF, m4);
            mNL = fmaxf(mNL, m4);
        }
    }
    #pragma unroll
    for (int off = 32; off; off >>= 1) {
        mA  = fmaxf(mA,  __shfl_down(mA,  off));
        mNF = fmaxf(mNF, __shfl_down(mNF, off));
        mNL = fmaxf(mNL, __shfl_down(mNL, off));
    }
    __shared__ float red[3][4];
    const int wid = tid >> 6;
    if ((tid & 63) == 0) { red[0][wid] = mA; red[1][wid] = mNF; red[2][wid] = mNL; }
    __syncthreads();
    if (tid == 0) {
        mA  = fmaxf(fmaxf(red[0][0], red[0][1]), fmaxf(red[0][2], red[0][3]));
        mNF = fmaxf(fmaxf(red[1][0], red[1][1]), fmaxf(red[1][2], red[1][3]));
        mNL = fmaxf(fmaxf(red[2][0], red[2][1]), fmaxf(red[2][2], red[2][3]));
        // k=0 uses x[-1..L-2] -> exclude last; k=1 all; k=2 uses x[1..L] -> exclude first
        float* p = wsf + (ic*32 + b*4 + ch)*3;
        p[0] = mNL; p[1] = mA; p[2] = mNF;   // unique slot per block
    }
}

// ---------------- pass 2: one tiny block computes scales + quantized A ----------------
__global__ __launch_bounds__(256) void prep_kernel(const float* __restrict__ w,
                                                   float* __restrict__ wsf,
                                                   unsigned int* __restrict__ wsa) {
    __shared__ float scl[192];
    __shared__ float red[256];
    const int tid = threadIdx.x;
    float ax = 0.0f, aw = 0.0f;
    if (tid < 192) {
        float wsc = 0.0f;
        #pragma unroll 8
        for (int o = 0; o < 64; ++o) wsc = fmaxf(wsc, fabsf(w[o*192 + tid]));
        int ic = tid / 3, k = tid - ic*3;
        float asc = 0.0f;
        #pragma unroll 8
        for (int q = 0; q < 32; ++q) asc = fmaxf(asc, wsf[(ic*32 + q)*3 + k]);
        float sc = sqrtf(asc) / sqrtf(wsc);    // act**0.5 / w**0.5
        if (sc == 0.0f) sc = 1.0f;
        scl[tid] = sc;
        ax = asc / sc;     // column max of |cols/scale| (monotone fp div)
        aw = wsc * sc;     // max |w*scale|
    }
    red[tid] = ax; __syncthreads();
    for (int s = 128; s; s >>= 1) { if (tid < s) red[tid] = fmaxf(red[tid], red[tid+s]); __syncthreads(); }
    float axm = red[0]; __syncthreads();
    red[tid] = aw; __syncthreads();
    for (int s = 128; s; s >>= 1) { if (tid < s) red[tid] = fmaxf(red[tid], red[tid+s]); __syncthreads(); }
    float awm = red[0];
    float s_x = (axm == 0.0f) ? 1.0f : axm / QMAXF;
    float s_w = (awm == 0.0f) ? 1.0f : awm / QMAXF;
    if (tid < 192) wsf[6144 + tid] = 1.0f / (scl[tid] * s_x);
    if (tid == 0)  wsf[6336] = s_x * s_w;
    __syncthreads();
    // quantize weights into MFMA A-fragment (16x16x64 i8) lane-chunk order
    for (int idx = tid; idx < 3072; idx += 256) {
        int oc = idx / 48, dwi = idx - oc*48, j0 = dwi*4;
        unsigned pk = 0;
        #pragma unroll
        for (int bb = 0; bb < 4; ++bb) {
            int j = j0 + bb;
            float q = rintf((w[oc*192 + j] * scl[j]) / s_w);  // ref op order
            q = fminf(fmaxf(q, -QMAXF), QMAXF);
            pk |= (((unsigned)(int)q) & 255u) << (8*bb);
        }
        int mt = oc >> 4, m = oc & 15, c = j0 >> 4, s = c >> 2, kq = c & 3;
        wsa[((mt*3 + s)*64 + kq*16 + m)*4 + ((j0 & 15) >> 2)] = pk;
    }
}

// ---------------- pass 3: conv as i8 MFMA GEMM, double-buffered LDS ----------------
// Per tile: quant(regs) -> write bsm[buf] -> ONE barrier -> prefetch next x
// -> ds_read+MFMA -> store. Buffer alternation removes the leading barrier
// (tile-i barrier orders reuse two tiles later; compiler drains lgkm at barrier).
// Granule XOR swizzle G^=(G>>6)&7 both sides: writes 2-way (free), reads a
// permutation within 8-lane groups (conflict-free).
__global__ __launch_bounds__(256) void conv_mfma_kernel(const float* __restrict__ x,
                                                        const float* __restrict__ bias,
                                                        const float* __restrict__ wsf,
                                                        const v4i* __restrict__ wsa,
                                                        float* __restrict__ out) {
    __shared__ int bsm[2][3072];
    const int tid  = threadIdx.x;
    const int b    = blockIdx.y;
    const int lane = tid & 63;
    const int wv   = tid >> 6;

    // per-thread staging roles
    const int tq  = tid & 15;      // owns t = 4*tq .. 4*tq+3 (tile-local)
    const int icg = tid >> 4;      // owns ic = 4*icg .. 4*icg+3  (j = 12*icg..+11)
    const int tb  = tq << 2;

    // first tile's x loads issued first (longest latency)
    float xv[4][6];                // [ici][t-1 .. t+4]
    {
        const int t0 = (blockIdx.x * TPB) << 6;
        #pragma unroll
        for (int ici = 0; ici < 4; ++ici) {
            const float* rowp = x + (((size_t)(b*64 + icg*4 + ici)) << 15) + t0 + tb;
            float4 mid = *(const float4*)rowp;
            float lm = (t0 + tb > 0)           ? rowp[-1] : 0.0f;
            float rp = (t0 + tb + 4 < L_LEN)   ? rowp[4]  : 0.0f;
            xv[ici][0] = lm;    xv[ici][1] = mid.x; xv[ici][2] = mid.y;
            xv[ici][3] = mid.z; xv[ici][4] = mid.w; xv[ici][5] = rp;
        }
    }

    // A fragments: 4 m-tiles x 3 k-steps (L2-hot)
    v4i afrag[12];
    #pragma unroll
    for (int i = 0; i < 12; ++i) afrag[i] = wsa[i*64 + lane];

    float rv[12];
    #pragma unroll
    for (int jj = 0; jj < 12; ++jj) rv[jj] = wsf[6144 + icg*12 + jj];
    const float sxw = wsf[6336];

    for (int it = 0; it < TPB; ++it) {
        const int t0c = (blockIdx.x * TPB + it) << 6;
        const int buf = it & 1;

        // quantize current tile from xv into registers (consumes xv)
        unsigned pkq[12];
        #pragma unroll
        for (int dt = 0; dt < 4; ++dt) {
            #pragma unroll
            for (int dw = 0; dw < 3; ++dw) {
                unsigned pk = 0;
                #pragma unroll
                for (int bb = 0; bb < 4; ++bb) {
                    int jloc = dw*4 + bb;           // j = 12*icg + jloc = 3*ic + k
                    int ici = jloc / 3, k = jloc - ici*3;
                    float q = rintf(xv[ici][dt + k] * rv[jloc]);
                    q = fminf(fmaxf(q, -QMAXF), QMAXF);
                    pk |= (((unsigned)(int)q) & 255u) << (8*bb);
                }
                pkq[dt*3 + dw] = pk;
            }
        }

        // write into this tile's buffer (other buffer may still be read)
        #pragma unroll
        for (int dt = 0; dt < 4; ++dt) {
            int t = tb + dt, wt = t >> 4, n = t & 15;
            #pragma unroll
            for (int dw = 0; dw < 3; ++dw) {
                int j0 = icg*12 + dw*4;
                int c = j0 >> 4, s = c >> 2, kq = c & 3;
                int G = (wt*3 + s)*64 + kq*16 + n;
                G ^= (G >> 6) & 7;                 // bank swizzle
                bsm[buf][G*4 + ((j0 & 15) >> 2)] = (int)pkq[dt*3 + dw];
            }
        }
        __syncthreads();                           // single barrier per tile

        // prefetch next tile's x (in flight across MFMA + epilogue)
        if (it + 1 < TPB) {
            const int t0n = (blockIdx.x * TPB + it + 1) << 6;
            #pragma unroll
            for (int ici = 0; ici < 4; ++ici) {
                const float* rowp = x + (((size_t)(b*64 + icg*4 + ici)) << 15) + t0n + tb;
                float4 mid = *(const float4*)rowp;
                float lm = (t0n + tb > 0)          ? rowp[-1] : 0.0f;
                float rp = (t0n + tb + 4 < L_LEN)  ? rowp[4]  : 0.0f;
                xv[ici][0] = lm;    xv[ici][1] = mid.x; xv[ici][2] = mid.y;
                xv[ici][3] = mid.z; xv[ici][4] = mid.w; xv[ici][5] = rp;
            }
        }

        // ---- MFMA ----
        v4i acc[4];
        #pragma unroll
        for (int mt = 0; mt < 4; ++mt) acc[mt] = (v4i){0,0,0,0};
        const v4i* bsmv = (const v4i*)bsm[buf];
        #pragma unroll
        for (int s = 0; s < 3; ++s) {
            int Gr = (wv*3 + s)*64 + lane;
            Gr ^= (wv*3 + s) & 7;                  // same swizzle ((Gr>>6)&7)
            v4i bf = bsmv[Gr];
            #pragma unroll
            for (int mt = 0; mt < 4; ++mt)
                acc[mt] = __builtin_amdgcn_mfma_i32_16x16x64_i8(afrag[mt*3 + s], bf, acc[mt], 0, 0, 0);
        }

        // ---- epilogue: C/D layout col=lane&15 -> t, row=(lane>>4)*4+i -> oc ----
        const int tg   = t0c + (wv << 4) + (lane & 15);
        const int rowq = (lane >> 4) << 2;
        #pragma unroll
        for (int mt = 0; mt < 4; ++mt) {
            #pragma unroll
            for (int i = 0; i < 4; ++i) {
                int oc = mt*16 + rowq + i;
                out[(((size_t)(b*64 + oc)) << 15) + tg] = (float)acc[mt][i] * sxw + bias[oc];
            }
        }
    }
}

extern "C" void kernel_launch(void* const* d_in, const int* in_sizes, int n_in,
                              void* d_out, int out_size, void* d_ws, size_t ws_size,
                              hipStream_t stream) {
    const float* x    = (const float*)d_in[0];
    const float* w    = (const float*)d_in[1];
    const float* bias = (const float*)d_in[2];
    float* out = (float*)d_out;
    float* wsf = (float*)d_ws;
    unsigned int* wsa = (unsigned int*)((char*)d_ws + 32768);

    hipLaunchKernelGGL(actamax_kernel,   dim3(64, 8, 4), dim3(256), 0, stream, x, wsf);
    hipLaunchKernelGGL(prep_kernel,      dim3(1),        dim3(256), 0, stream, w, wsf, wsa);
    hipLaunchKernelGGL(conv_mfma_kernel, dim3(128, 8),   dim3(256), 0, stream,
                       x, bias, wsf, (const v4i*)wsa, out);
}

// Round 8
// 136.216 us; speedup vs baseline: 1.1501x; 1.1501x over previous
//
#include <hip/hip_runtime.h>

#define L_LEN 32768
#define QMAXF 127.0f
#define TPB 4   // conv tiles (of 64 t) per block

typedef __attribute__((ext_vector_type(4))) int v4i;

// ws layout (floats):
//   [0..6144)    : amax partials, slot (ic*32 + b*4 + ch)*3 + k  (64*8*4*3)
//                  plain stores, every slot written exactly once -> no memset
//   [6144..6336) : rv_j = 1/(scl_j * s_x), j = 3*ic+k (ic-major)
//   [6336]       : s_x * s_w
//   byte 32768+  : wsa A fragments (quantized weights, i8, MFMA lane-chunk order)

// ---------------- pass 1: per-(ic,b,quarter) abs-max partials ----------------
// grid (64,8,4): quarter-row per block, 8 float4/thread batched into regs
// (guaranteed 8-deep MLP), wave reduce, plain stores to unique slots.
__global__ __launch_bounds__(256) void actamax_kernel(const float* __restrict__ x,
                                                      float* __restrict__ wsf) {
    const int ic = blockIdx.x, b = blockIdx.y, ch = blockIdx.z;
    const int tid = threadIdx.x;
    const float4* row = (const float4*)(x + ((size_t)(b*64 + ic) << 15));
    const int base = ch*2048 + tid;

    float4 vbuf[8];
    #pragma unroll
    for (int i = 0; i < 8; ++i) vbuf[i] = row[base + i*256];   // all 8 in flight

    float mA = 0.0f, mNF = 0.0f, mNL = 0.0f;   // all, no-first(t>0), no-last(t<L-1)
    #pragma unroll
    for (int i = 0; i < 8; ++i) {
        const int f = base + i*256;
        float4 v = vbuf[i];
        float ax = fabsf(v.x), ay = fabsf(v.y), az = fabsf(v.z), aw = fabsf(v.w);
        float m4 = fmaxf(fmaxf(ax, ay), fmaxf(az, aw));
        mA = fmaxf(mA, m4);
        if (f == 0) {                      // only ch==0,i==0,tid==0
            mNF = fmaxf(mNF, fmaxf(ay, fmaxf(az, aw)));
            mNL = fmaxf(mNL, m4);
        } else if (f == 8191) {            // only ch==3,i==7,tid==255
            mNF = fmaxf(mNF, m4);
            mNL = fmaxf(mNL, fmaxf(ax, fmaxf(ay, az)));
        } else {
            mNF = fmaxf(mNF, m4);
            mNL = fmaxf(mNL, m4);
        }
    }
    #pragma unroll
    for (int off = 32; off; off >>= 1) {
        mA  = fmaxf(mA,  __shfl_down(mA,  off));
        mNF = fmaxf(mNF, __shfl_down(mNF, off));
        mNL = fmaxf(mNL, __shfl_down(mNL, off));
    }
    __shared__ float red[3][4];
    const int wid = tid >> 6;
    if ((tid & 63) == 0) { red[0][wid] = mA; red[1][wid] = mNF; red[2][wid] = mNL; }
    __syncthreads();
    if (tid == 0) {
        mA  = fmaxf(fmaxf(red[0][0], red[0][1]), fmaxf(red[0][2], red[0][3]));
        mNF = fmaxf(fmaxf(red[1][0], red[1][1]), fmaxf(red[1][2], red[1][3]));
        mNL = fmaxf(fmaxf(red[2][0], red[2][1]), fmaxf(red[2][2], red[2][3]));
        // k=0 uses x[-1..L-2] -> exclude last; k=1 all; k=2 uses x[1..L] -> exclude first
        float* p = wsf + (ic*32 + b*4 + ch)*3;
        p[0] = mNL; p[1] = mA; p[2] = mNF;   // unique slot per block
    }
}

// ---------------- pass 2: scales + quantized A, one block x 1024 thr ----------------
// 4 threads per column: wsc split 16-deep x4, asc split 8-deep x4, shfl_xor
// combine (exact: fmax over identical element sets).
__global__ __launch_bounds__(1024) void prep_kernel(const float* __restrict__ w,
                                                    float* __restrict__ wsf,
                                                    unsigned int* __restrict__ wsa) {
    __shared__ float scl[192];
    __shared__ float redA[16], redW[16];
    __shared__ float sxs[2];
    const int tid = threadIdx.x;
    const int wid = tid >> 6;
    float ax = 0.0f, aw = 0.0f;
    if (tid < 768) {
        const int col = tid >> 2, sub = tid & 3;
        float wsc = 0.0f;
        #pragma unroll
        for (int o = 0; o < 16; ++o) wsc = fmaxf(wsc, fabsf(w[(sub*16 + o)*192 + col]));
        const int ic = col / 3, k = col - ic*3;
        float asc = 0.0f;
        #pragma unroll
        for (int q = 0; q < 8; ++q) asc = fmaxf(asc, wsf[(ic*32 + sub*8 + q)*3 + k]);
        wsc = fmaxf(wsc, __shfl_xor(wsc, 1));
        wsc = fmaxf(wsc, __shfl_xor(wsc, 2));
        asc = fmaxf(asc, __shfl_xor(asc, 1));
        asc = fmaxf(asc, __shfl_xor(asc, 2));
        float sc = sqrtf(asc) / sqrtf(wsc);    // act**0.5 / w**0.5
        if (sc == 0.0f) sc = 1.0f;
        if (sub == 0) scl[col] = sc;
        ax = asc / sc;     // column max of |cols/scale| (monotone fp div)
        aw = wsc * sc;     // max |w*scale|
    }
    #pragma unroll
    for (int off = 32; off; off >>= 1) {
        ax = fmaxf(ax, __shfl_down(ax, off));
        aw = fmaxf(aw, __shfl_down(aw, off));
    }
    if ((tid & 63) == 0) { redA[wid] = ax; redW[wid] = aw; }
    __syncthreads();
    if (tid == 0) {
        float axm = redA[0], awm = redW[0];
        #pragma unroll
        for (int i = 1; i < 16; ++i) { axm = fmaxf(axm, redA[i]); awm = fmaxf(awm, redW[i]); }
        sxs[0] = (axm == 0.0f) ? 1.0f : axm / QMAXF;
        sxs[1] = (awm == 0.0f) ? 1.0f : awm / QMAXF;
    }
    __syncthreads();
    const float s_x = sxs[0], s_w = sxs[1];
    if (tid < 192) wsf[6144 + tid] = 1.0f / (scl[tid] * s_x);
    if (tid == 0)  wsf[6336] = s_x * s_w;
    // quantize weights into MFMA A-fragment (16x16x64 i8) lane-chunk order
    for (int idx = tid; idx < 3072; idx += 1024) {
        int oc = idx / 48, dwi = idx - oc*48, j0 = dwi*4;
        unsigned pk = 0;
        #pragma unroll
        for (int bb = 0; bb < 4; ++bb) {
            int j = j0 + bb;
            float q = rintf((w[oc*192 + j] * scl[j]) / s_w);  // ref op order
            q = fminf(fmaxf(q, -QMAXF), QMAXF);
            pk |= (((unsigned)(int)q) & 255u) << (8*bb);
        }
        int mt = oc >> 4, m = oc & 15, c = j0 >> 4, s = c >> 2, kq = c & 3;
        wsa[((mt*3 + s)*64 + kq*16 + m)*4 + ((j0 & 15) >> 2)] = pk;
    }
}

// ---------------- pass 3: conv as i8 MFMA GEMM, double-buffered LDS ----------------
// Halo via wave shfl: threads with equal icg are consecutive lanes, so the
// t-1 / t+4 window elements live in the neighbor lane's mid float4. Only the
// icg-subgroup boundary lanes (tq==0 / tq==15 -- exactly where shfl crosses
// subgroups) fall back to exec-masked scalar loads. 12 full-wave VMEM ops ->
// 4 + 8 thin. Values bit-identical to reloading.
__global__ __launch_bounds__(256) void conv_mfma_kernel(const float* __restrict__ x,
                                                        const float* __restrict__ bias,
                                                        const float* __restrict__ wsf,
                                                        const v4i* __restrict__ wsa,
                                                        float* __restrict__ out) {
    __shared__ int bsm[2][3072];
    const int tid  = threadIdx.x;
    const int b    = blockIdx.y;
    const int lane = tid & 63;
    const int wv   = tid >> 6;

    // per-thread staging roles
    const int tq  = tid & 15;      // owns t = 4*tq .. 4*tq+3 (tile-local)
    const int icg = tid >> 4;      // owns ic = 4*icg .. 4*icg+3  (j = 12*icg..+11)
    const int tb  = tq << 2;
    const bool isL = (tq == 0), isR = (tq == 15);

    const float* xbase = x + (((size_t)(b*64 + icg*4)) << 15) + tb;   // +ici*32768 +t0

    // first tile's x loads issued first (longest latency)
    float xm[4][4], xe[4][2];
    {
        const int t0 = (blockIdx.x * TPB) << 6;
        #pragma unroll
        for (int ici = 0; ici < 4; ++ici) {
            float4 mid = *(const float4*)(xbase + (((size_t)ici) << 15) + t0);
            xm[ici][0] = mid.x; xm[ici][1] = mid.y; xm[ici][2] = mid.z; xm[ici][3] = mid.w;
        }
        if (isL) {
            #pragma unroll
            for (int ici = 0; ici < 4; ++ici)
                xe[ici][0] = (t0 > 0) ? xbase[(((size_t)ici) << 15) + t0 - 1] : 0.0f;
        }
        if (isR) {
            #pragma unroll
            for (int ici = 0; ici < 4; ++ici)
                xe[ici][1] = (t0 + 64 < L_LEN) ? xbase[(((size_t)ici) << 15) + t0 + 4] : 0.0f;
        }
    }

    // A fragments: 4 m-tiles x 3 k-steps (L2-hot)
    v4i afrag[12];
    #pragma unroll
    for (int i = 0; i < 12; ++i) afrag[i] = wsa[i*64 + lane];

    float rv[12];
    #pragma unroll
    for (int jj = 0; jj < 12; ++jj) rv[jj] = wsf[6144 + icg*12 + jj];
    const float sxw = wsf[6336];

    for (int it = 0; it < TPB; ++it) {
        const int t0c = (blockIdx.x * TPB + it) << 6;
        const int buf = it & 1;

        // assemble 6-wide window via shfl halo (bit-identical values)
        float wdw[4][6];
        #pragma unroll
        for (int ici = 0; ici < 4; ++ici) {
            float lmv = __shfl_up(xm[ici][3], 1);
            float rpv = __shfl_down(xm[ici][0], 1);
            wdw[ici][0] = isL ? xe[ici][0] : lmv;
            wdw[ici][1] = xm[ici][0];
            wdw[ici][2] = xm[ici][1];
            wdw[ici][3] = xm[ici][2];
            wdw[ici][4] = xm[ici][3];
            wdw[ici][5] = isR ? xe[ici][1] : rpv;
        }

        // quantize current tile into registers
        unsigned pkq[12];
        #pragma unroll
        for (int dt = 0; dt < 4; ++dt) {
            #pragma unroll
            for (int dw = 0; dw < 3; ++dw) {
                unsigned pk = 0;
                #pragma unroll
                for (int bb = 0; bb < 4; ++bb) {
                    int jloc = dw*4 + bb;           // j = 12*icg + jloc = 3*ic + k
                    int ici = jloc / 3, k = jloc - ici*3;
                    float q = rintf(wdw[ici][dt + k] * rv[jloc]);
                    q = fminf(fmaxf(q, -QMAXF), QMAXF);
                    pk |= (((unsigned)(int)q) & 255u) << (8*bb);
                }
                pkq[dt*3 + dw] = pk;
            }
        }

        // write into this tile's buffer (other buffer may still be read)
        #pragma unroll
        for (int dt = 0; dt < 4; ++dt) {
            int t = tb + dt, wt = t >> 4, n = t & 15;
            #pragma unroll
            for (int dw = 0; dw < 3; ++dw) {
                int j0 = icg*12 + dw*4;
                int c = j0 >> 4, s = c >> 2, kq = c & 3;
                int G = (wt*3 + s)*64 + kq*16 + n;
                G ^= (G >> 6) & 7;                 // bank swizzle
                bsm[buf][G*4 + ((j0 & 15) >> 2)] = (int)pkq[dt*3 + dw];
            }
        }
        __syncthreads();                           // single barrier per tile

        // prefetch next tile's x (in flight across MFMA + epilogue)
        if (it + 1 < TPB) {
            const int t0n = (blockIdx.x * TPB + it + 1) << 6;
            #pragma unroll
            for (int ici = 0; ici < 4; ++ici) {
                float4 mid = *(const float4*)(xbase + (((size_t)ici) << 15) + t0n);
                xm[ici][0] = mid.x; xm[ici][1] = mid.y; xm[ici][2] = mid.z; xm[ici][3] = mid.w;
            }
            if (isL) {                             // t0n >= 64 > 0 always
                #pragma unroll
                for (int ici = 0; ici < 4; ++ici)
                    xe[ici][0] = xbase[(((size_t)ici) << 15) + t0n - 1];
            }
            if (isR) {
                #pragma unroll
                for (int ici = 0; ici < 4; ++ici)
                    xe[ici][1] = (t0n + 64 < L_LEN) ? xbase[(((size_t)ici) << 15) + t0n + 4] : 0.0f;
            }
        }

        // ---- MFMA ----
        v4i acc[4];
        #pragma unroll
        for (int mt = 0; mt < 4; ++mt) acc[mt] = (v4i){0,0,0,0};
        const v4i* bsmv = (const v4i*)bsm[buf];
        #pragma unroll
        for (int s = 0; s < 3; ++s) {
            int Gr = (wv*3 + s)*64 + lane;
            Gr ^= (wv*3 + s) & 7;                  // same swizzle ((Gr>>6)&7)
            v4i bf = bsmv[Gr];
            #pragma unroll
            for (int mt = 0; mt < 4; ++mt)
                acc[mt] = __builtin_amdgcn_mfma_i32_16x16x64_i8(afrag[mt*3 + s], bf, acc[mt], 0, 0, 0);
        }

        // ---- epilogue: C/D layout col=lane&15 -> t, row=(lane>>4)*4+i -> oc ----
        const int tg   = t0c + (wv << 4) + (lane & 15);
        const int rowq = (lane >> 4) << 2;
        #pragma unroll
        for (int mt = 0; mt < 4; ++mt) {
            #pragma unroll
            for (int i = 0; i < 4; ++i) {
                int oc = mt*16 + rowq + i;
                out[(((size_t)(b*64 + oc)) << 15) + tg] = (float)acc[mt][i] * sxw + bias[oc];
            }
        }
    }
}

extern "C" void kernel_launch(void* const* d_in, const int* in_sizes, int n_in,
                              void* d_out, int out_size, void* d_ws, size_t ws_size,
                              hipStream_t stream) {
    const float* x    = (const float*)d_in[0];
    const float* w    = (const float*)d_in[1];
    const float* bias = (const float*)d_in[2];
    float* out = (float*)d_out;
    float* wsf = (float*)d_ws;
    unsigned int* wsa = (unsigned int*)((char*)d_ws + 32768);

    hipLaunchKernelGGL(actamax_kernel,   dim3(64, 8, 4), dim3(256),  0, stream, x, wsf);
    hipLaunchKernelGGL(prep_kernel,      dim3(1),        dim3(1024), 0, stream, w, wsf, wsa);
    hipLaunchKernelGGL(conv_mfma_kernel, dim3(128, 8),   dim3(256),  0, stream,
                       x, bias, wsf, (const v4i*)wsa, out);
}